// Round 1
// baseline (136.162 us; speedup 1.0000x reference)
//
#include <hip/hip_runtime.h>
#include <math.h>

#define DIMS 160
#define PLANE (DIMS*DIMS)          // 25600
#define NB 2
#define RH 7
#define RL 4
#define KH 15
#define KL 9
#define TSX 16
#define TSY 32
#define NTX (DIMS/TSX)             // 10
#define NTY (DIMS/TSY)             // 5
#define CZ 32                      // z outputs per block (was 16): halo amortization 1.875 -> 1.4375
#define NCH (DIMS/CZ)              // 5
#define NSTEPS (CZ + 2*RH)         // 46 planes marched
#define YHR (TSY + 2*RH)           // 46 raw halo rows
#define SR 40                      // sRaw row stride (floats): b128 pattern 2-way-free, 16B aligned
#define SH 52                      // sXh col stride: 52%32=20, gcd(20,32)=4 -> b64/b128 reads uniform
#define SL 44                      // sXl col stride: 44%32=12, same property
#define RAWSZ (YHR*SR)             // 1840
#define XHSZ (TSX*SH)              // 832
#define XLSZ (TSX*SL)              // 704
#define NBLK (NTX*NTY*NCH*NB)      // 500 blocks

struct DoGW { float gl[KL]; float gh[KH]; };

// v8: LDS-issue-bound fix. All DS ops vectorized (b64/b128), 2 y-cols per yconv
// thread, CZ=32, unroll-5 z-march for ring-shift renaming, role-balanced waves:
//   waves 0-3: yconv (2 cols, float2 reads)   waves 4-6: xconv (float4 reads)
//   waves 5-8: loader (2x float4 global + 2x b128 stage)
// Distance-2 pipeline and 1 barrier/plane kept from v7. Numerics identical.
__global__ __launch_bounds__(512, 4)
void dog_v8(const float* __restrict__ X, float* __restrict__ out, DoGW w) {
  __shared__ __align__(16) float sRaw[2][RAWSZ];   // 14.7 KB
  __shared__ __align__(16) float sXh[2][XHSZ];     // 6.7 KB
  __shared__ __align__(16) float sXl[2][XLSZ];     // 5.6 KB  (27.0 KB total)

  const int bid = blockIdx.x;
  const int xt = bid % NTX;
  const int yt = (bid / NTX) % NTY;
  const int zc = (bid / (NTX * NTY)) % NCH;
  const int b  = bid / (NTX * NTY * NCH);
  const int x0 = xt * TSX, y0 = yt * TSY, z0 = zc * CZ;
  const float* Xb = X + (size_t)b * DIMS * PLANE;
  const int tid = threadIdx.x;
  const bool xfast = (x0 >= 8) && (x0 + 24 <= DIMS);

  // ---- yconv role: threads 0..255, 2 adjacent y columns each ----
  const bool y_on = tid < 256;
  const int cx  = tid & 15;
  const int cy0 = 2 * ((tid >> 4) & 15);           // even -> 8B-aligned float2 windows
  const int hb = cx * SH + cy0;
  const int lb = cx * SL + cy0;
  float* const obase = out + ((size_t)b * DIMS * PLANE) + (size_t)(y0 + cy0) * DIMS + (x0 + cx);

  // ---- xconv role: threads 256..439 (184 = 46 rows x 4 quads) ----
  const bool x_on = (tid >= 256) && (tid < 256 + YHR * 4);
  const int xu = tid - 256;
  const int xr = xu >> 2, xq = xu & 3;

  // ---- loader role: threads 328..511 (184 = 46 rows x 4), 8 floats each ----
  const bool l_on = tid >= (512 - YHR * 4);
  const int lu = tid - (512 - YHR * 4);
  const int lrow = lu >> 2, lt = lu & 3;
  const int lyg = min(max(y0 + lrow - RH, 0), DIMS - 1);
  const int lxb = x0 - 8 + 4 * lt;

  float4 vA, vB;                                   // plane in flight (distance-2)

  auto loadP = [&](int s) {
    const int zsrc = min(max(z0 - RH + s, 0), DIMS - 1);
    const float* rowp = Xb + ((size_t)zsrc * DIMS + lyg) * DIMS;
    if (xfast) {
      vA = *(const float4*)(rowp + lxb);
      vB = *(const float4*)(rowp + lxb + 16);
    } else {
      vA.x = rowp[min(max(lxb + 0, 0), DIMS - 1)];
      vA.y = rowp[min(max(lxb + 1, 0), DIMS - 1)];
      vA.z = rowp[min(max(lxb + 2, 0), DIMS - 1)];
      vA.w = rowp[min(max(lxb + 3, 0), DIMS - 1)];
      vB.x = rowp[min(max(lxb + 16, 0), DIMS - 1)];
      vB.y = rowp[min(max(lxb + 17, 0), DIMS - 1)];
      vB.z = rowp[min(max(lxb + 18, 0), DIMS - 1)];
      vB.w = rowp[min(max(lxb + 19, 0), DIMS - 1)];
    }
  };
  auto stageP = [&](int buf) {
    float* p = &sRaw[buf][lrow * SR + 4 * lt];     // 16B aligned; uniform bank spread
    *(float4*)(p) = vA;
    *(float4*)(p + 16) = vB;
  };

  // z rings (scatter form, shifts renamed by the unrolled march)
  float accH0[KH], accH1[KH], accL0[KL + 3], accL1[KL + 3];
  #pragma unroll
  for (int i = 0; i < KH; ++i) { accH0[i] = 0.f; accH1[i] = 0.f; }
  #pragma unroll
  for (int i = 0; i < KL + 3; ++i) { accL0[i] = 0.f; accL1[i] = 0.f; }

  auto consumeQ = [&](int q) {
    const int qb = q & 1;
    float f[16], g[10];
    #pragma unroll
    for (int j = 0; j < 8; ++j) {                  // ds_read_b64, conflict-free (SH%32=20)
      float2 t = *(const float2*)&sXh[qb][hb + 2 * j];
      f[2 * j] = t.x; f[2 * j + 1] = t.y;
    }
    #pragma unroll
    for (int j = 0; j < 5; ++j) {
      float2 t = *(const float2*)&sXl[qb][lb + 2 * j];
      g[2 * j] = t.x; g[2 * j + 1] = t.y;
    }
    float ph0 = 0.f, ph1 = 0.f, pl0 = 0.f, pl1 = 0.f;
    #pragma unroll
    for (int j = 0; j < KH; ++j) {
      ph0 = fmaf(w.gh[j], f[j], ph0);
      ph1 = fmaf(w.gh[j], f[j + 1], ph1);
    }
    #pragma unroll
    for (int j = 0; j < KL; ++j) {
      pl0 = fmaf(w.gl[j], g[j], pl0);
      pl1 = fmaf(w.gl[j], g[j + 1], pl1);
    }
    #pragma unroll
    for (int i = 0; i < KH; ++i) {
      accH0[i] = fmaf(w.gh[KH - 1 - i], ph0, accH0[i]);
      accH1[i] = fmaf(w.gh[KH - 1 - i], ph1, accH1[i]);
    }
    #pragma unroll
    for (int i = 3; i < KL + 3; ++i) {
      accL0[i] = fmaf(w.gl[KL + 2 - i], pl0, accL0[i]);
      accL1[i] = fmaf(w.gl[KL + 2 - i], pl1, accL1[i]);
    }
    if (q >= 2 * RH) {
      float* op = obase + (size_t)(z0 + q - 2 * RH) * PLANE;
      op[0]    = accL0[0] - accH0[0];
      op[DIMS] = accL1[0] - accH1[0];
    }
    #pragma unroll
    for (int i = 0; i < KH - 1; ++i) { accH0[i] = accH0[i + 1]; accH1[i] = accH1[i + 1]; }
    accH0[KH - 1] = 0.f; accH1[KH - 1] = 0.f;
    #pragma unroll
    for (int i = 0; i < KL + 2; ++i) { accL0[i] = accL0[i + 1]; accL1[i] = accL1[i + 1]; }
    accL0[KL + 2] = 0.f; accL1[KL + 2] = 0.f;
  };

  auto xconvP = [&](int cur) {
    const float* p = &sRaw[cur][xr * SR + 4 * xq];
    float v[20];
    #pragma unroll
    for (int j = 0; j < 5; ++j) {                  // ds_read_b128, 2-way-free (SR=40)
      float4 t = *(const float4*)(p + 4 * j);
      v[4 * j] = t.x; v[4 * j + 1] = t.y; v[4 * j + 2] = t.z; v[4 * j + 3] = t.w;
    }
    #pragma unroll
    for (int c = 0; c < 4; ++c) {                  // high, K=15
      float a = 0.f;
      #pragma unroll
      for (int k = 0; k < KH; ++k) a = fmaf(w.gh[k], v[c + 1 + k], a);
      sXh[cur][(4 * xq + c) * SH + xr] = a;
    }
    if (xr >= 3 && xr <= 42) {
      #pragma unroll
      for (int c = 0; c < 4; ++c) {                // low, K=9
        float a = 0.f;
        #pragma unroll
        for (int k = 0; k < KL; ++k) a = fmaf(w.gl[k], v[c + 4 + k], a);
        sXl[cur][(4 * xq + c) * SL + (xr - 3)] = a;
      }
    }
  };

  // prologue: plane 0 staged direct; plane 1 held in vA/vB
  if (l_on) { loadP(0); stageP(0); loadP(1); }
  __syncthreads();                                 // B(0): sRaw[0] ready

  // main march: 45 = 9 x 5 steps; unroll-5 renames ring shifts inside the window
  for (int sb = 0; sb < NSTEPS - 1; sb += 5) {
    #pragma unroll
    for (int u = 0; u < 5; ++u) {
      const int s = sb + u;
      const int cur = s & 1;
      if (l_on) {
        if (s + 1 < NSTEPS) stageP(1 - cur);       // plane s+1 (loaded 1 segment ago)
        if (s + 2 < NSTEPS) loadP(s + 2);          // in flight a full segment
      }
      if (y_on && s >= 1) consumeQ(s - 1);         // yconv + z-scatter + store, lagged 1
      if (x_on) xconvP(cur);                       // plane s -> sX[cur]
      __syncthreads();                             // B(s+1)
    }
  }
  // final step s = 45 (no stage/load remaining)
  {
    if (y_on) consumeQ(NSTEPS - 2);
    if (x_on) xconvP((NSTEPS - 1) & 1);
    __syncthreads();
    if (y_on) consumeQ(NSTEPS - 1);                // epilogue: final plane + last stores
  }
}

extern "C" void kernel_launch(void* const* d_in, const int* in_sizes, int n_in,
                              void* d_out, int out_size, void* d_ws, size_t ws_size,
                              hipStream_t stream) {
  const float* X = (const float*)d_in[0];
  float* out = (float*)d_out;

  DoGW w;
  {
    double s = 0.0;
    for (int i = 0; i < KL; ++i) {
      double t = i - (KL - 1) / 2.0;
      double g = exp(-(t * t) / (2.0 * 1.0 * 1.0));
      w.gl[i] = (float)g; s += g;
    }
    for (int i = 0; i < KL; ++i) w.gl[i] = (float)((double)w.gl[i] / s);
    s = 0.0;
    for (int i = 0; i < KH; ++i) {
      double t = i - (KH - 1) / 2.0;
      double g = exp(-(t * t) / (2.0 * 1.6 * 1.6));
      w.gh[i] = (float)g; s += g;
    }
    for (int i = 0; i < KH; ++i) w.gh[i] = (float)((double)w.gh[i] / s);
  }

  dog_v8<<<NBLK, 512, 0, stream>>>(X, out, w);
}

// Round 2
// 128.803 us; speedup vs baseline: 1.0571x; 1.0571x over previous
//
#include <hip/hip_runtime.h>
#include <math.h>

#define DIMS 160
#define PLANE (DIMS*DIMS)          // 25600
#define NB 2
#define RH 7
#define RL 4
#define KH 15
#define KL 9
#define TSX 16
#define TSY 32
#define NTX (DIMS/TSX)             // 10
#define NTY (DIMS/TSY)             // 5
#define CZ 32                      // z outputs per block: halo amortization 1.4375
#define NCH (DIMS/CZ)              // 5
#define NSTEPS (CZ + 2*RH)         // 46 planes marched
#define YHR (TSY + 2*RH)           // 46 raw halo rows
// Bank geometry (the v8 bug): for a 16-lane phase reading b64 at cx*S, need
// gcd(S mod 32, 32) == 2 so the 16 start banks are 16 DISTINCT evens and the
// word-pairs tile all 32 banks once. S=50 (18*cx perm) and S=42 (10*cx perm).
// For b128 at xr*SR + 4*xq need SR mod 32 == 16: xr-even starts {0,4,8,12},
// xr-odd {16,20,24,28} -> every 8-lane/128B phase tiles all 32 banks once.
#define SR 48                      // sRaw row stride
#define SH 50                      // sXh col stride (v7-proven geometry, now b64)
#define SL 42                      // sXl col stride
#define RAWSZ (YHR*SR)             // 2208
#define XHSZ (TSX*SH)              // 800
#define XLSZ (TSX*SL)              // 672
#define NBLK (NTX*NTY*NCH*NB)      // 500 blocks

struct DoGW { float gl[KL]; float gh[KH]; };

// v9 = v8 (vectorized DS ops, 2-col yconv, CZ=32, unroll-5, distance-2 z-march)
// with conflict-free strides restored under the vector widths.
//   waves 0-3: yconv (2 cols, b64 reads)   waves 4-6: xconv (b128 reads)
//   waves 5-8: loader (2x float4 global + 2x b128 stage)
__global__ __launch_bounds__(512, 4)
void dog_v9(const float* __restrict__ X, float* __restrict__ out, DoGW w) {
  __shared__ __align__(16) float sRaw[2][RAWSZ];   // 17.3 KB
  __shared__ __align__(16) float sXh[2][XHSZ];     // 6.25 KB
  __shared__ __align__(16) float sXl[2][XLSZ];     // 5.25 KB  (28.8 KB total)

  const int bid = blockIdx.x;
  const int xt = bid % NTX;
  const int yt = (bid / NTX) % NTY;
  const int zc = (bid / (NTX * NTY)) % NCH;
  const int b  = bid / (NTX * NTY * NCH);
  const int x0 = xt * TSX, y0 = yt * TSY, z0 = zc * CZ;
  const float* Xb = X + (size_t)b * DIMS * PLANE;
  const int tid = threadIdx.x;
  const bool xfast = (x0 >= 8) && (x0 + 24 <= DIMS);

  // ---- yconv role: threads 0..255, 2 adjacent y columns each ----
  const bool y_on = tid < 256;
  const int cx  = tid & 15;
  const int cy0 = 2 * ((tid >> 4) & 15);           // even -> 8B-aligned b64 windows
  const int hb = cx * SH + cy0;
  const int lb = cx * SL + cy0;
  float* const obase = out + ((size_t)b * DIMS * PLANE) + (size_t)(y0 + cy0) * DIMS + (x0 + cx);

  // ---- xconv role: threads 256..439 (184 = 46 rows x 4 quads) ----
  const bool x_on = (tid >= 256) && (tid < 256 + YHR * 4);
  const int xu = tid - 256;
  const int xr = xu >> 2, xq = xu & 3;

  // ---- loader role: threads 328..511 (184 = 46 rows x 4), 8 floats each ----
  const bool l_on = tid >= (512 - YHR * 4);
  const int lu = tid - (512 - YHR * 4);
  const int lrow = lu >> 2, lt = lu & 3;
  const int lyg = min(max(y0 + lrow - RH, 0), DIMS - 1);
  const int lxb = x0 - 8 + 4 * lt;

  float4 vA, vB;                                   // plane in flight (distance-2)

  auto loadP = [&](int s) {
    const int zsrc = min(max(z0 - RH + s, 0), DIMS - 1);
    const float* rowp = Xb + ((size_t)zsrc * DIMS + lyg) * DIMS;
    if (xfast) {
      vA = *(const float4*)(rowp + lxb);
      vB = *(const float4*)(rowp + lxb + 16);
    } else {
      vA.x = rowp[min(max(lxb + 0, 0), DIMS - 1)];
      vA.y = rowp[min(max(lxb + 1, 0), DIMS - 1)];
      vA.z = rowp[min(max(lxb + 2, 0), DIMS - 1)];
      vA.w = rowp[min(max(lxb + 3, 0), DIMS - 1)];
      vB.x = rowp[min(max(lxb + 16, 0), DIMS - 1)];
      vB.y = rowp[min(max(lxb + 17, 0), DIMS - 1)];
      vB.z = rowp[min(max(lxb + 18, 0), DIMS - 1)];
      vB.w = rowp[min(max(lxb + 19, 0), DIMS - 1)];
    }
  };
  auto stageP = [&](int buf) {
    float* p = &sRaw[buf][lrow * SR + 4 * lt];     // 16B aligned; phases tile 32 banks
    *(float4*)(p) = vA;
    *(float4*)(p + 16) = vB;
  };

  // z rings (scatter form, shifts renamed by the unrolled march)
  float accH0[KH], accH1[KH], accL0[KL + 3], accL1[KL + 3];
  #pragma unroll
  for (int i = 0; i < KH; ++i) { accH0[i] = 0.f; accH1[i] = 0.f; }
  #pragma unroll
  for (int i = 0; i < KL + 3; ++i) { accL0[i] = 0.f; accL1[i] = 0.f; }

  auto consumeQ = [&](int q) {
    const int qb = q & 1;
    float f[16], g[10];
    #pragma unroll
    for (int j = 0; j < 8; ++j) {                  // ds_read_b64: 16 distinct even start banks/phase
      float2 t = *(const float2*)&sXh[qb][hb + 2 * j];
      f[2 * j] = t.x; f[2 * j + 1] = t.y;
    }
    #pragma unroll
    for (int j = 0; j < 5; ++j) {
      float2 t = *(const float2*)&sXl[qb][lb + 2 * j];
      g[2 * j] = t.x; g[2 * j + 1] = t.y;
    }
    float ph0 = 0.f, ph1 = 0.f, pl0 = 0.f, pl1 = 0.f;
    #pragma unroll
    for (int j = 0; j < KH; ++j) {
      ph0 = fmaf(w.gh[j], f[j], ph0);
      ph1 = fmaf(w.gh[j], f[j + 1], ph1);
    }
    #pragma unroll
    for (int j = 0; j < KL; ++j) {
      pl0 = fmaf(w.gl[j], g[j], pl0);
      pl1 = fmaf(w.gl[j], g[j + 1], pl1);
    }
    #pragma unroll
    for (int i = 0; i < KH; ++i) {
      accH0[i] = fmaf(w.gh[KH - 1 - i], ph0, accH0[i]);
      accH1[i] = fmaf(w.gh[KH - 1 - i], ph1, accH1[i]);
    }
    #pragma unroll
    for (int i = 3; i < KL + 3; ++i) {
      accL0[i] = fmaf(w.gl[KL + 2 - i], pl0, accL0[i]);
      accL1[i] = fmaf(w.gl[KL + 2 - i], pl1, accL1[i]);
    }
    if (q >= 2 * RH) {
      float* op = obase + (size_t)(z0 + q - 2 * RH) * PLANE;
      op[0]    = accL0[0] - accH0[0];
      op[DIMS] = accL1[0] - accH1[0];
    }
    #pragma unroll
    for (int i = 0; i < KH - 1; ++i) { accH0[i] = accH0[i + 1]; accH1[i] = accH1[i + 1]; }
    accH0[KH - 1] = 0.f; accH1[KH - 1] = 0.f;
    #pragma unroll
    for (int i = 0; i < KL + 2; ++i) { accL0[i] = accL0[i + 1]; accL1[i] = accL1[i + 1]; }
    accL0[KL + 2] = 0.f; accL1[KL + 2] = 0.f;
  };

  auto xconvP = [&](int cur) {
    const float* p = &sRaw[cur][xr * SR + 4 * xq];
    float v[20];
    #pragma unroll
    for (int j = 0; j < 5; ++j) {                  // ds_read_b128: each 8-lane phase tiles 32 banks
      float4 t = *(const float4*)(p + 4 * j);
      v[4 * j] = t.x; v[4 * j + 1] = t.y; v[4 * j + 2] = t.z; v[4 * j + 3] = t.w;
    }
    #pragma unroll
    for (int c = 0; c < 4; ++c) {                  // high, K=15
      float a = 0.f;
      #pragma unroll
      for (int k = 0; k < KH; ++k) a = fmaf(w.gh[k], v[c + 1 + k], a);
      sXh[cur][(4 * xq + c) * SH + xr] = a;        // scalar write: exactly 2-way = free
    }
    if (xr >= 3 && xr <= 42) {
      #pragma unroll
      for (int c = 0; c < 4; ++c) {                // low, K=9
        float a = 0.f;
        #pragma unroll
        for (int k = 0; k < KL; ++k) a = fmaf(w.gl[k], v[c + 4 + k], a);
        sXl[cur][(4 * xq + c) * SL + (xr - 3)] = a;
      }
    }
  };

  // prologue: plane 0 staged direct; plane 1 held in vA/vB
  if (l_on) { loadP(0); stageP(0); loadP(1); }
  __syncthreads();                                 // B(0): sRaw[0] ready

  // main march: 45 = 9 x 5 steps; unroll-5 renames ring shifts inside the window
  for (int sb = 0; sb < NSTEPS - 1; sb += 5) {
    #pragma unroll
    for (int u = 0; u < 5; ++u) {
      const int s = sb + u;
      const int cur = s & 1;
      if (l_on) {
        if (s + 1 < NSTEPS) stageP(1 - cur);       // plane s+1 (loaded 1 segment ago)
        if (s + 2 < NSTEPS) loadP(s + 2);          // in flight a full segment
      }
      if (y_on && s >= 1) consumeQ(s - 1);         // yconv + z-scatter + store, lagged 1
      if (x_on) xconvP(cur);                       // plane s -> sX[cur]
      __syncthreads();                             // B(s+1)
    }
  }
  // final step s = 45 (no stage/load remaining)
  {
    if (y_on) consumeQ(NSTEPS - 2);
    if (x_on) xconvP((NSTEPS - 1) & 1);
    __syncthreads();
    if (y_on) consumeQ(NSTEPS - 1);                // epilogue: final plane + last stores
  }
}

extern "C" void kernel_launch(void* const* d_in, const int* in_sizes, int n_in,
                              void* d_out, int out_size, void* d_ws, size_t ws_size,
                              hipStream_t stream) {
  const float* X = (const float*)d_in[0];
  float* out = (float*)d_out;

  DoGW w;
  {
    double s = 0.0;
    for (int i = 0; i < KL; ++i) {
      double t = i - (KL - 1) / 2.0;
      double g = exp(-(t * t) / (2.0 * 1.0 * 1.0));
      w.gl[i] = (float)g; s += g;
    }
    for (int i = 0; i < KL; ++i) w.gl[i] = (float)((double)w.gl[i] / s);
    s = 0.0;
    for (int i = 0; i < KH; ++i) {
      double t = i - (KH - 1) / 2.0;
      double g = exp(-(t * t) / (2.0 * 1.6 * 1.6));
      w.gh[i] = (float)g; s += g;
    }
    for (int i = 0; i < KH; ++i) w.gh[i] = (float)((double)w.gh[i] / s);
  }

  dog_v9<<<NBLK, 512, 0, stream>>>(X, out, w);
}